// Round 4
// baseline (380.701 us; speedup 1.0000x reference)
//
#include <hip/hip_runtime.h>
#include <hip/hip_cooperative_groups.h>
#include <cstdint>

namespace cg = cooperative_groups;
typedef unsigned long long u64;

#define HW   12544      // 112*112
#define NPIX 401408     // 32*12544

// Fused binary-conv + BN-stats + BN/hardtanh/residual, one cooperative kernel.
// Grid 448 = 32 n x 14 (8-row tiles). Block 256.
// stg[r] holds sign-mask row h0-1+r (64 channel bits per pixel), zero halo.
__global__ __launch_bounds__(256, 2) void k_fused(
    const float* __restrict__ x, const float* __restrict__ Wt,
    const float* __restrict__ gamma, const float* __restrict__ beta,
    float* __restrict__ out,
    u64* __restrict__ S1, u64* __restrict__ S2,
    float* __restrict__ alpha9, u64* __restrict__ wbits) {
  __shared__ u64 stg[10][114];
  __shared__ int red1[256];
  __shared__ int red2[256];
  __shared__ float mscS[64];
  __shared__ float b3S[9][64];
  cg::grid_group grid = cg::this_grid();
  int b = blockIdx.x, t = threadIdx.x;
  int n = b / 14, h0 = (b % 14) * 8;

  // ---------------- Phase A: zero stg, pack x tile + W taps ----------------
  {
    u64* stg1 = &stg[0][0];
    for (int i = t; i < 1140; i += 256) stg1[i] = 0;
  }
  __syncthreads();
  {
    int rlo = (h0 == 0) ? 1 : 0;          // stg row of first valid image row
    int rhi = (h0 == 104) ? 8 : 9;
    int P = (rhi - rlo + 1) * 112;        // pixels to pack (1008 or 1120)
    const float* base = x + (size_t)(n * 64) * HW + (h0 - 1 + rlo) * 112;
    u64 m0x = 0, m0y = 0, m0z = 0, m0w = 0;
    u64 m1x = 0, m1y = 0, m1z = 0, m1w = 0;
    int p0 = 4 * t, p1 = 1024 + 4 * t;
    bool a0 = p0 < P, a1 = p1 < P;
    for (int c = 0; c < 64; ++c) {
      const float* cb = base + (size_t)c * HW;
      if (a0) {
        float4 v = *reinterpret_cast<const float4*>(cb + p0);
        m0x |= (u64)(v.x > 0.f) << c; m0y |= (u64)(v.y > 0.f) << c;
        m0z |= (u64)(v.z > 0.f) << c; m0w |= (u64)(v.w > 0.f) << c;
      }
      if (a1) {
        float4 v = *reinterpret_cast<const float4*>(cb + p1);
        m1x |= (u64)(v.x > 0.f) << c; m1y |= (u64)(v.y > 0.f) << c;
        m1z |= (u64)(v.z > 0.f) << c; m1w |= (u64)(v.w > 0.f) << c;
      }
    }
    if (a0) { int r = rlo + p0 / 112, col = p0 % 112;   // 112%4==0: same row
      stg[r][col+1] = m0x; stg[r][col+2] = m0y; stg[r][col+3] = m0z; stg[r][col+4] = m0w; }
    if (a1) { int r = rlo + p1 / 112, col = p1 % 112;
      stg[r][col+1] = m1x; stg[r][col+2] = m1y; stg[r][col+3] = m1z; stg[r][col+4] = m1w; }
  }
  if (b < 9) {                            // block k packs W tap k + alpha partial
    int lane = t & 63, wv = t >> 6;
    for (int i = 0; i < 16; ++i) {
      int co = wv * 16 + i;
      float v = Wt[((size_t)co * 64 + lane) * 9 + b];   // OIHW, lane = cin
      float s = fabsf(v);
#pragma unroll
      for (int off = 32; off > 0; off >>= 1) s += __shfl_xor(s, off);
      u64 msk = __ballot(v > 0.f);        // bit cin = sign(+)
      if (lane == 0) { wbits[b * 64 + co] = msk; alpha9[b * 64 + co] = s; }
    }
  } else if (b == 9) {
    if (t < 64) S1[t] = 0; else if (t < 128) S2[t - 64] = 0;
  }

  grid.sync();

  // ---------------- Phase B: integer conv stats (S1, S2) ------------------
  {
    int c = t & 63, wv = t >> 6;
    u64 wm0 = wbits[c],       wm1 = wbits[64 + c],  wm2 = wbits[128 + c];
    u64 wm3 = wbits[192 + c], wm4 = wbits[256 + c], wm5 = wbits[320 + c];
    u64 wm6 = wbits[384 + c], wm7 = wbits[448 + c], wm8 = wbits[512 + c];
    int pw0 = __popcll(wm0), pw1 = __popcll(wm1), pw2 = __popcll(wm2);
    int pw3 = __popcll(wm3), pw5 = __popcll(wm5);
    int pw6 = __popcll(wm6), pw7 = __popcll(wm7), pw8 = __popcll(wm8);
    int vtop = 192 - 2 * (pw0 + pw1 + pw2);
    int vbot = 192 - 2 * (pw6 + pw7 + pw8);
    int hlft = 192 - 2 * (pw0 + pw3 + pw6);
    int hrgt = 192 - 2 * (pw2 + pw5 + pw8);
    int cTL = 64 - 2 * pw0, cTR = 64 - 2 * pw2, cBL = 64 - 2 * pw6, cBR = 64 - 2 * pw8;
    int s1 = 0, s2 = 0;
    for (int it = 0; it < 56; ++it) {
      int idx = wv * 56 + it;             // wave-uniform; covers 8 rows x 28 strips
      int r = idx / 28, w0i = (idx % 28) * 4;
      int h = h0 + r;
      u64 A0 = stg[r][w0i],   A1 = stg[r][w0i+1], A2 = stg[r][w0i+2];
      u64 A3 = stg[r][w0i+3], A4 = stg[r][w0i+4], A5 = stg[r][w0i+5];
      u64 B0 = stg[r+1][w0i],   B1 = stg[r+1][w0i+1], B2 = stg[r+1][w0i+2];
      u64 B3 = stg[r+1][w0i+3], B4 = stg[r+1][w0i+4], B5 = stg[r+1][w0i+5];
      u64 C0 = stg[r+2][w0i],   C1 = stg[r+2][w0i+1], C2 = stg[r+2][w0i+2];
      u64 C3 = stg[r+2][w0i+3], C4 = stg[r+2][w0i+4], C5 = stg[r+2][w0i+5];
      int rt = (h == 0) ? vtop : ((h == 111) ? vbot : 0);
      int lc = hlft - ((h == 0) ? cTL : 0) - ((h == 111) ? cBL : 0);
      int rc = hrgt - ((h == 0) ? cTR : 0) - ((h == 111) ? cBR : 0);
      int corr0 = rt + ((w0i == 0) ? lc : 0);
      int corr3 = rt + ((w0i == 108) ? rc : 0);
#define SUM9(a0,a1,a2,b0,b1,b2,c0,c1,c2)                                     \
      (__popcll((a0)^wm0)+__popcll((a1)^wm1)+__popcll((a2)^wm2)              \
      +__popcll((b0)^wm3)+__popcll((b1)^wm4)+__popcll((b2)^wm5)              \
      +__popcll((c0)^wm6)+__popcll((c1)^wm7)+__popcll((c2)^wm8))
      int I0 = 576 - 2 * SUM9(A0,A1,A2,B0,B1,B2,C0,C1,C2) - corr0;
      int I1 = 576 - 2 * SUM9(A1,A2,A3,B1,B2,B3,C1,C2,C3) - rt;
      int I2 = 576 - 2 * SUM9(A2,A3,A4,B2,B3,B4,C2,C3,C4) - rt;
      int I3 = 576 - 2 * SUM9(A3,A4,A5,B3,B4,B5,C3,C4,C5) - corr3;
#undef SUM9
      s1 += I0 + I1 + I2 + I3;
      s2 += I0*I0 + I1*I1 + I2*I2 + I3*I3;   // <= 56*4*576^2, fits int32
    }
    red1[t] = s1; red2[t] = s2;
    __syncthreads();
    if (t < 64) {
      int a1s = red1[t] + red1[t+64] + red1[t+128] + red1[t+192];
      int a2s = red2[t] + red2[t+64] + red2[t+128] + red2[t+192];
      atomicAdd(&S1[t], (u64)(long long)a1s);
      atomicAdd(&S2[t], (u64)(long long)a2s);
    }
  }

  grid.sync();

  // ---------------- Phase C: BN prep + conv + epilogue --------------------
  if (t < 64) {
    int pw[9]; float asum = 0.f;
#pragma unroll
    for (int k = 0; k < 9; ++k) {
      pw[k] = __popcll(wbits[k * 64 + t]);
      asum += alpha9[k * 64 + t];
    }
    double al = (double)asum * (1.0 / 576.0);
    long long s1v = (long long)S1[t], s2v = (long long)S2[t];
    double inv = 1.0 / (double)NPIX;
    double mean = (double)s1v * inv;
    double var = (double)s2v * inv - mean * mean;
    double sc = (double)gamma[t] * al / sqrt(al * al * var + 1e-5);
    double bi = (double)beta[t] - sc * mean;
    mscS[t] = (float)(-2.0 * sc);
#pragma unroll
    for (int ht = 0; ht < 3; ++ht)
#pragma unroll
      for (int wt = 0; wt < 3; ++wt) {
        int corr = 0;
#pragma unroll
        for (int k = 0; k < 9; ++k) {
          int dh = k / 3 - 1, dw = k % 3 - 1;
          bool inval = (ht == 0 && dh < 0) || (ht == 2 && dh > 0) ||
                       (wt == 0 && dw < 0) || (wt == 2 && dw > 0);
          if (inval) corr += 64 - 2 * pw[k];
        }
        b3S[ht * 3 + wt][t] = (float)((576.0 - corr) * sc + bi);
      }
  }
  __syncthreads();

  if (t < 224) {
    int r = t / 28, w0i = (t % 28) * 4;   // horizontal 4-px strip
    int h = h0 + r;
    u64 A0 = stg[r][w0i],   A1 = stg[r][w0i+1], A2 = stg[r][w0i+2];
    u64 A3 = stg[r][w0i+3], A4 = stg[r][w0i+4], A5 = stg[r][w0i+5];
    u64 B0 = stg[r+1][w0i],   B1 = stg[r+1][w0i+1], B2 = stg[r+1][w0i+2];
    u64 B3 = stg[r+1][w0i+3], B4 = stg[r+1][w0i+4], B5 = stg[r+1][w0i+5];
    u64 C0 = stg[r+2][w0i],   C1 = stg[r+2][w0i+1], C2 = stg[r+2][w0i+2];
    u64 C3 = stg[r+2][w0i+3], C4 = stg[r+2][w0i+4], C5 = stg[r+2][w0i+5];
    int row_t = (h == 0) ? 0 : ((h == 111) ? 2 : 1);
    bool wl = (w0i == 0), wr = (w0i == 108);
    int tm = row_t * 3 + 1;
    const float* xb = x + (size_t)(n * 64) * HW + h * 112 + w0i;
    float* ob = out + (size_t)(n * 64) * HW + h * 112 + w0i;
#pragma unroll 2
    for (int cc = 0; cc < 64; ++cc) {
      // cc is thread-uniform -> uniform (scalar-path) weight loads
      u64 w0 = wbits[cc],       w1 = wbits[64 + cc],  w2 = wbits[128 + cc];
      u64 w3 = wbits[192 + cc], w4 = wbits[256 + cc], w5 = wbits[320 + cc];
      u64 w6 = wbits[384 + cc], w7 = wbits[448 + cc], w8 = wbits[512 + cc];
#define SUM9(a0,a1,a2,b0,b1,b2,c0,c1,c2)                                     \
      (__popcll((a0)^w0)+__popcll((a1)^w1)+__popcll((a2)^w2)                 \
      +__popcll((b0)^w3)+__popcll((b1)^w4)+__popcll((b2)^w5)                 \
      +__popcll((c0)^w6)+__popcll((c1)^w7)+__popcll((c2)^w8))
      int s0 = SUM9(A0,A1,A2,B0,B1,B2,C0,C1,C2);
      int s1 = SUM9(A1,A2,A3,B1,B2,B3,C1,C2,C3);
      int s2 = SUM9(A2,A3,A4,B2,B3,B4,C2,C3,C4);
      int s3 = SUM9(A3,A4,A5,B3,B4,B5,C3,C4,C5);
#undef SUM9
      float msc = mscS[cc];
      float bmid = b3S[tm][cc];
      float bj0 = wl ? b3S[row_t * 3][cc] : bmid;
      float bj3 = wr ? b3S[row_t * 3 + 2][cc] : bmid;
      float4 xv = *reinterpret_cast<const float4*>(xb + (size_t)cc * HW);
      float o0 = fminf(fmaxf(fmaf((float)s0, msc, bj0),  -1.f), 1.f) + xv.x;
      float o1 = fminf(fmaxf(fmaf((float)s1, msc, bmid), -1.f), 1.f) + xv.y;
      float o2 = fminf(fmaxf(fmaf((float)s2, msc, bmid), -1.f), 1.f) + xv.z;
      float o3 = fminf(fmaxf(fmaf((float)s3, msc, bj3),  -1.f), 1.f) + xv.w;
      *reinterpret_cast<float4*>(ob + (size_t)cc * HW) = make_float4(o0, o1, o2, o3);
    }
  }
}

// ---------------------------------------------------------------------------
extern "C" void kernel_launch(void* const* d_in, const int* in_sizes, int n_in,
                              void* d_out, int out_size, void* d_ws, size_t ws_size,
                              hipStream_t stream) {
  const float* x     = (const float*)d_in[0];
  const float* W     = (const float*)d_in[1];
  const float* gamma = (const float*)d_in[2];
  const float* beta  = (const float*)d_in[3];
  float* out = (float*)d_out;

  char* ws = (char*)d_ws;
  u64*   S1     = (u64*)(ws + 0);       // 64 * 8 B
  u64*   S2     = (u64*)(ws + 512);     // 64 * 8 B
  float* alpha9 = (float*)(ws + 1024);  // 9 * 64 * 4 B
  u64*   wbits  = (u64*)(ws + 4096);    // 576 * 8 B

  void* args[] = {(void*)&x, (void*)&W, (void*)&gamma, (void*)&beta, (void*)&out,
                  (void*)&S1, (void*)&S2, (void*)&alpha9, (void*)&wbits};
  hipLaunchCooperativeKernel((const void*)k_fused, dim3(448), dim3(256),
                             args, 0, stream);
}

// Round 6
// 369.076 us; speedup vs baseline: 1.0315x; 1.0315x over previous
//
#include <hip/hip_runtime.h>
#include <cstdint>

typedef unsigned long long u64;
typedef unsigned int u32;
typedef int v4i __attribute__((ext_vector_type(4)));

#define HW   12544            // 112*112
#define NPIX 401408           // 32*12544
#define PROW 114              // padded cols
#define PRB  (PROW * 64)      // padded row bytes = 7296
#define PNB  (114 * PRB)      // per-image bytes = 831744

// ---------------------------------------------------------------------------
// k_pack: blocks [0,392): NCHW f32 -> padded NHWC i8 signs (+1/-1), 4 px/thread.
//         block 392: W -> wi8[tap][cout][cin] i8 signs + alpha partials + zero S1/S2.
// Border of xi8 stays 0 from the preceding memset => conv zero-padding is native.
// ---------------------------------------------------------------------------
__global__ __launch_bounds__(256) void k_pack(const float* __restrict__ x,
                                              const float* __restrict__ W,
                                              unsigned char* __restrict__ xi8,
                                              unsigned char* __restrict__ wi8,
                                              float* __restrict__ alpha9,
                                              u64* __restrict__ stats) {
  int b = blockIdx.x, t = threadIdx.x;
  if (b < 392) {
    int gp = (b * 256 + t) * 4;          // 392*256*4 = NPIX exactly
    int n = gp / HW, p = gp % HW;
    int h = p / 112, w = p % 112;        // 112%4==0: 4 px same row
    const float* xp = x + (size_t)(n * 64) * HW + p;
    u32 wd[4][16];
#pragma unroll
    for (int px = 0; px < 4; ++px)
#pragma unroll
      for (int q = 0; q < 16; ++q) wd[px][q] = 0;
#pragma unroll
    for (int c = 0; c < 64; ++c) {       // full unroll: wd indices compile-time
      float4 v = *reinterpret_cast<const float4*>(xp + (size_t)c * HW);
      u32 sh = (u32)(c & 3) * 8; int q = c >> 2;
      wd[0][q] |= (v.x > 0.f ? 0x01u : 0xFFu) << sh;
      wd[1][q] |= (v.y > 0.f ? 0x01u : 0xFFu) << sh;
      wd[2][q] |= (v.z > 0.f ? 0x01u : 0xFFu) << sh;
      wd[3][q] |= (v.w > 0.f ? 0x01u : 0xFFu) << sh;
    }
    uint4* sp = reinterpret_cast<uint4*>(
        xi8 + (size_t)n * PNB + (size_t)(h + 1) * PRB + (size_t)(w + 1) * 64);
#pragma unroll
    for (int px = 0; px < 4; ++px)
#pragma unroll
      for (int q4 = 0; q4 < 4; ++q4)
        sp[px * 4 + q4] = make_uint4(wd[px][4*q4], wd[px][4*q4+1],
                                     wd[px][4*q4+2], wd[px][4*q4+3]);
  } else {
    if (t < 128) stats[t] = 0;           // zero S1[64], S2[64]
    for (int i = t; i < 576; i += 256) { // (tap, cout) pairs
      int tap = i / 64, co = i % 64;
      u32 wdw[16];
#pragma unroll
      for (int q = 0; q < 16; ++q) wdw[q] = 0;
      float asum = 0.f;
#pragma unroll
      for (int ci = 0; ci < 64; ++ci) {
        float wv = W[((size_t)co * 64 + ci) * 9 + tap];   // OIHW
        asum += fabsf(wv);
        wdw[ci >> 2] |= (wv > 0.f ? 0x01u : 0xFFu) << ((u32)(ci & 3) * 8);
      }
      uint4* dp = reinterpret_cast<uint4*>(wi8 + tap * 4096 + co * 64);
#pragma unroll
      for (int q4 = 0; q4 < 4; ++q4)
        dp[q4] = make_uint4(wdw[4*q4], wdw[4*q4+1], wdw[4*q4+2], wdw[4*q4+3]);
      alpha9[i] = asum;                  // alpha = (sum over 9 taps)/576, later
    }
  }
}

// ---------------------------------------------------------------------------
// Shared conv core: wave = one (n,h) image row, 7 tiles of 16 px, all 64 couts.
// A = wi8 (cout x cin, per tap) in 36 VGPRs; B = xi8 patch (cin x px) loaded
// per tap from padded NHWC (zero pad native). D[row=cout][col=px].
// ---------------------------------------------------------------------------
#define MFMA9(ACC0, ACC1, ACC2, ACC3)                                          \
  _Pragma("unroll")                                                            \
  for (int k = 0; k < 9; ++k) {                                                \
    ACC0 = __builtin_amdgcn_mfma_i32_16x16x64_i8(A[0][k], B[k], ACC0, 0, 0, 0);\
    ACC1 = __builtin_amdgcn_mfma_i32_16x16x64_i8(A[1][k], B[k], ACC1, 0, 0, 0);\
    ACC2 = __builtin_amdgcn_mfma_i32_16x16x64_i8(A[2][k], B[k], ACC2, 0, 0, 0);\
    ACC3 = __builtin_amdgcn_mfma_i32_16x16x64_i8(A[3][k], B[k], ACC3, 0, 0, 0);\
  }

__global__ __launch_bounds__(256, 2) void k_stats(const unsigned char* __restrict__ xi8,
                                                  const unsigned char* __restrict__ wi8,
                                                  u64* __restrict__ S1,
                                                  u64* __restrict__ S2) {
  __shared__ int sh1[4][64];
  __shared__ int sh2[4][64];
  int b = blockIdx.x, t = threadIdx.x, wv = t >> 6, l = t & 63;
  int lo = (l & 15) * 64 + (l >> 4) * 16;        // byte offset within 16x64 frag
  v4i A[4][9];
#pragma unroll
  for (int g = 0; g < 4; ++g)
#pragma unroll
    for (int k = 0; k < 9; ++k)
      A[g][k] = *reinterpret_cast<const v4i*>(wi8 + k * 4096 + g * 1024 + lo);

  int tid = b * 4 + wv;                          // 0..3583 = 32 n x 112 rows
  int n = tid / 112, h = tid % 112;
  const unsigned char* rowp = xi8 + (size_t)n * PNB + (size_t)(h + 1) * PRB + 64 + lo;
  int s1a[4][4], s2a[4][4];
#pragma unroll
  for (int g = 0; g < 4; ++g)
#pragma unroll
    for (int j = 0; j < 4; ++j) { s1a[g][j] = 0; s2a[g][j] = 0; }

  for (int wt = 0; wt < 7; ++wt) {
    const unsigned char* bp = rowp + wt * 1024;
    v4i B[9];
#pragma unroll
    for (int k = 0; k < 9; ++k) {
      int dh = k / 3 - 1, dw = k % 3 - 1;
      B[k] = *reinterpret_cast<const v4i*>(bp + dh * PRB + dw * 64);
    }
    v4i acc0 = {0,0,0,0}, acc1 = {0,0,0,0}, acc2 = {0,0,0,0}, acc3 = {0,0,0,0};
    MFMA9(acc0, acc1, acc2, acc3)
#define SEPI(G, ACC)                                                           \
    _Pragma("unroll")                                                          \
    for (int j = 0; j < 4; ++j) { int I = ACC[j]; s1a[G][j] += I; s2a[G][j] += I * I; }
    SEPI(0, acc0) SEPI(1, acc1) SEPI(2, acc2) SEPI(3, acc3)
#undef SEPI
  }
  // reduce over the 16 px lanes (l&15), then across waves via LDS
  int lo4 = (l >> 4) * 4;
#pragma unroll
  for (int g = 0; g < 4; ++g)
#pragma unroll
    for (int j = 0; j < 4; ++j) {
      int v1 = s1a[g][j], v2 = s2a[g][j];
      v1 += __shfl_xor(v1, 1); v1 += __shfl_xor(v1, 2);
      v1 += __shfl_xor(v1, 4); v1 += __shfl_xor(v1, 8);
      v2 += __shfl_xor(v2, 1); v2 += __shfl_xor(v2, 2);
      v2 += __shfl_xor(v2, 4); v2 += __shfl_xor(v2, 8);
      if ((l & 15) == 0) { int c = g * 16 + lo4 + j; sh1[wv][c] = v1; sh2[wv][c] = v2; }
    }
  __syncthreads();
  if (t < 64) {
    long long a1 = (long long)sh1[0][t] + sh1[1][t] + sh1[2][t] + sh1[3][t];
    long long a2 = (long long)sh2[0][t] + sh2[1][t] + sh2[2][t] + sh2[3][t];
    atomicAdd(&S1[t], (u64)a1);          // two's-complement wrap = exact i64 sum
    atomicAdd(&S2[t], (u64)a2);
  }
}

__global__ __launch_bounds__(256, 2) void k_final(const float* __restrict__ x,
                                                  const unsigned char* __restrict__ xi8,
                                                  const unsigned char* __restrict__ wi8,
                                                  const u64* __restrict__ S1,
                                                  const u64* __restrict__ S2,
                                                  const float* __restrict__ alpha9,
                                                  const float* __restrict__ gamma,
                                                  const float* __restrict__ beta,
                                                  float* __restrict__ out) {
  __shared__ float2 scb[64];
  int b = blockIdx.x, t = threadIdx.x, wv = t >> 6, l = t & 63;
  if (t < 64) {
    float asum = 0.f;
#pragma unroll
    for (int k = 0; k < 9; ++k) asum += alpha9[k * 64 + t];
    double al = (double)asum * (1.0 / 576.0);
    long long s1v = (long long)S1[t], s2v = (long long)S2[t];
    double inv = 1.0 / (double)NPIX;
    double mean = (double)s1v * inv;
    double var = (double)s2v * inv - mean * mean;
    double sc = (double)gamma[t] * al / sqrt(al * al * var + 1e-5);
    scb[t] = make_float2((float)sc, (float)((double)beta[t] - sc * mean));
  }
  __syncthreads();

  int lo = (l & 15) * 64 + (l >> 4) * 16;
  v4i A[4][9];
#pragma unroll
  for (int g = 0; g < 4; ++g)
#pragma unroll
    for (int k = 0; k < 9; ++k)
      A[g][k] = *reinterpret_cast<const v4i*>(wi8 + k * 4096 + g * 1024 + lo);

  int tid = b * 4 + wv;
  int n = tid / 112, h = tid % 112;
  const unsigned char* rowp = xi8 + (size_t)n * PNB + (size_t)(h + 1) * PRB + 64 + lo;
  size_t pixbase = (size_t)(n * 64) * HW + (size_t)h * 112 + (l & 15);
  int lo4 = (l >> 4) * 4;

  for (int wt = 0; wt < 7; ++wt) {
    const unsigned char* bp = rowp + wt * 1024;
    v4i B[9];
#pragma unroll
    for (int k = 0; k < 9; ++k) {
      int dh = k / 3 - 1, dw = k % 3 - 1;
      B[k] = *reinterpret_cast<const v4i*>(bp + dh * PRB + dw * 64);
    }
    v4i acc0 = {0,0,0,0}, acc1 = {0,0,0,0}, acc2 = {0,0,0,0}, acc3 = {0,0,0,0};
    MFMA9(acc0, acc1, acc2, acc3)
    size_t pb = pixbase + wt * 16;
#define EPI(G, ACC)                                                            \
    _Pragma("unroll")                                                          \
    for (int j = 0; j < 4; ++j) {                                              \
      int c = G * 16 + lo4 + j;                                                \
      float2 sb = scb[c];                                                      \
      float o = fmaf((float)ACC[j], sb.x, sb.y);                               \
      o = fminf(fmaxf(o, -1.f), 1.f);                                          \
      size_t a = pb + (size_t)c * HW;                                          \
      out[a] = o + x[a];                                                       \
    }
    EPI(0, acc0) EPI(1, acc1) EPI(2, acc2) EPI(3, acc3)
#undef EPI
  }
}

// ---------------------------------------------------------------------------
extern "C" void kernel_launch(void* const* d_in, const int* in_sizes, int n_in,
                              void* d_out, int out_size, void* d_ws, size_t ws_size,
                              hipStream_t stream) {
  const float* x     = (const float*)d_in[0];
  const float* W     = (const float*)d_in[1];
  const float* gamma = (const float*)d_in[2];
  const float* beta  = (const float*)d_in[3];
  float* out = (float*)d_out;

  char* ws = (char*)d_ws;
  u64*           S1     = (u64*)(ws + 0);      // 64 * 8 B
  u64*           S2     = (u64*)(ws + 512);    // 64 * 8 B
  float*         alpha9 = (float*)(ws + 1024); // 576 * 4 B
  unsigned char* wi8    = (unsigned char*)(ws + 4096);   // 9*64*64 = 36864 B
  unsigned char* xi8    = (unsigned char*)(ws + 65536);  // 32*PNB = 26.6 MB

  hipMemsetAsync(xi8, 0, (size_t)32 * PNB, stream);      // zero-pad border
  hipLaunchKernelGGL(k_pack, dim3(393), dim3(256), 0, stream,
                     x, W, xi8, wi8, alpha9, (u64*)ws);
  hipLaunchKernelGGL(k_stats, dim3(896), dim3(256), 0, stream, xi8, wi8, S1, S2);
  hipLaunchKernelGGL(k_final, dim3(896), dim3(256), 0, stream,
                     x, xi8, wi8, S1, S2, alpha9, gamma, beta, out);
}

// Round 7
// 350.863 us; speedup vs baseline: 1.0850x; 1.0519x over previous
//
#include <hip/hip_runtime.h>
#include <cstdint>

typedef unsigned long long u64;
typedef unsigned int u32;
typedef int v4i __attribute__((ext_vector_type(4)));

#define HW   12544            // 112*112
#define NPIX 401408           // 32*12544
#define PROW 114              // padded cols
#define PRB  (PROW * 64)      // padded row bytes = 7296
#define PNB  (114 * PRB)      // per-image bytes = 831744

// ---------------------------------------------------------------------------
// k_pack: blocks [0,784): NCHW f32 -> padded NHWC i8 signs (+1/-1), 2 px/thread.
//         blocks [784,816): zero the pad border of image (b-784) (replaces the
//         26.6 MB memset: only ~29 KB/image of border actually needs zeroing).
//         block 816: W -> wi8[tap][cout][cin] i8 signs + alpha partials + S1/S2=0.
// ---------------------------------------------------------------------------
__global__ __launch_bounds__(256) void k_pack(const float* __restrict__ x,
                                              const float* __restrict__ W,
                                              unsigned char* __restrict__ xi8,
                                              unsigned char* __restrict__ wi8,
                                              float* __restrict__ alpha9,
                                              u64* __restrict__ stats) {
  int b = blockIdx.x, t = threadIdx.x;
  if (b < 784) {
    int gp = (b * 256 + t) * 2;          // 784*256*2 = NPIX exactly
    int n = gp / HW, p = gp % HW;
    int h = p / 112, w = p % 112;        // p even, 112 even: both px same row
    const float* xp = x + (size_t)(n * 64) * HW + p;
    u32 wd[2][16];
#pragma unroll
    for (int px = 0; px < 2; ++px)
#pragma unroll
      for (int q = 0; q < 16; ++q) wd[px][q] = 0;
#pragma unroll
    for (int c = 0; c < 64; ++c) {
      float2 v = *reinterpret_cast<const float2*>(xp + (size_t)c * HW);
      u32 sh = (u32)(c & 3) * 8; int q = c >> 2;
      wd[0][q] |= (v.x > 0.f ? 0x01u : 0xFFu) << sh;
      wd[1][q] |= (v.y > 0.f ? 0x01u : 0xFFu) << sh;
    }
    uint4* sp = reinterpret_cast<uint4*>(
        xi8 + (size_t)n * PNB + (size_t)(h + 1) * PRB + (size_t)(w + 1) * 64);
#pragma unroll
    for (int px = 0; px < 2; ++px)
#pragma unroll
      for (int q4 = 0; q4 < 4; ++q4)
        sp[px * 4 + q4] = make_uint4(wd[px][4*q4], wd[px][4*q4+1],
                                     wd[px][4*q4+2], wd[px][4*q4+3]);
  } else if (b < 816) {
    int n = b - 784;
    uint4 z = make_uint4(0, 0, 0, 0);
    uint4* img = reinterpret_cast<uint4*>(xi8 + (size_t)n * PNB);
    for (int i = t; i < 456; i += 256) {             // padded row 0
      img[i] = z;
      img[113 * (PRB / 16) + i] = z;                 // padded row 113
    }
    for (int i = t; i < 896; i += 256) {             // cols 0 & 113, rows 1..112
      int r = (i >> 3) + 1, side = (i >> 2) & 1, q = i & 3;
      img[r * (PRB / 16) + side * (113 * 4) + q] = z;
    }
  } else {
    if (t < 128) stats[t] = 0;           // zero S1[64], S2[64]
    for (int i = t; i < 576; i += 256) { // (tap, cout) pairs
      int tap = i / 64, co = i % 64;
      u32 wdw[16];
#pragma unroll
      for (int q = 0; q < 16; ++q) wdw[q] = 0;
      float asum = 0.f;
#pragma unroll
      for (int ci = 0; ci < 64; ++ci) {
        float wv = W[((size_t)co * 64 + ci) * 9 + tap];   // OIHW
        asum += fabsf(wv);
        wdw[ci >> 2] |= (wv > 0.f ? 0x01u : 0xFFu) << ((u32)(ci & 3) * 8);
      }
      uint4* dp = reinterpret_cast<uint4*>(wi8 + tap * 4096 + co * 64);
#pragma unroll
      for (int q4 = 0; q4 < 4; ++q4)
        dp[q4] = make_uint4(wdw[4*q4], wdw[4*q4+1], wdw[4*q4+2], wdw[4*q4+3]);
      alpha9[i] = asum;
    }
  }
}

// ---------------------------------------------------------------------------
// Conv core: wave = (image row, cout-half). A = 18 v4i (72 VGPR, resident).
// B = xi8 patch (cin x 16px) per tap, 1KB coalesced loads; zero pad native.
// ---------------------------------------------------------------------------
#define MFMA9_2(ACC0, ACC1)                                                    \
  _Pragma("unroll")                                                            \
  for (int k = 0; k < 9; ++k) {                                                \
    ACC0 = __builtin_amdgcn_mfma_i32_16x16x64_i8(A[0][k], B[k], ACC0, 0, 0, 0);\
    ACC1 = __builtin_amdgcn_mfma_i32_16x16x64_i8(A[1][k], B[k], ACC1, 0, 0, 0);\
  }

__global__ __launch_bounds__(256, 3) void k_stats(const unsigned char* __restrict__ xi8,
                                                  const unsigned char* __restrict__ wi8,
                                                  u64* __restrict__ S1,
                                                  u64* __restrict__ S2) {
  __shared__ int sh1[2][64];
  __shared__ int sh2[2][64];
  int b = blockIdx.x, t = threadIdx.x, wv = t >> 6, l = t & 63;
  int tid = b * 4 + wv;                  // 0..7167
  int row = tid >> 1, ch = tid & 1;      // row = n*112+h, ch = cout half
  int n = row / 112, h = row % 112;
  int lo = (l & 15) * 64 + (l >> 4) * 16;
  v4i A[2][9];
#pragma unroll
  for (int g = 0; g < 2; ++g)
#pragma unroll
    for (int k = 0; k < 9; ++k)
      A[g][k] = *reinterpret_cast<const v4i*>(wi8 + k * 4096 + (ch * 2 + g) * 1024 + lo);

  const unsigned char* rowp = xi8 + (size_t)n * PNB + (size_t)(h + 1) * PRB + 64 + lo;
  int s1a[2][4], s2a[2][4];
#pragma unroll
  for (int g = 0; g < 2; ++g)
#pragma unroll
    for (int j = 0; j < 4; ++j) { s1a[g][j] = 0; s2a[g][j] = 0; }

#pragma unroll 7
  for (int wt = 0; wt < 7; ++wt) {
    const unsigned char* bp = rowp + wt * 1024;
    v4i B[9];
#pragma unroll
    for (int k = 0; k < 9; ++k) {
      int dh = k / 3 - 1, dw = k % 3 - 1;
      B[k] = *reinterpret_cast<const v4i*>(bp + dh * PRB + dw * 64);
    }
    v4i acc0 = {0,0,0,0}, acc1 = {0,0,0,0};
    MFMA9_2(acc0, acc1)
#pragma unroll
    for (int j = 0; j < 4; ++j) {
      int I0 = acc0[j], I1 = acc1[j];
      s1a[0][j] += I0; s2a[0][j] += I0 * I0;
      s1a[1][j] += I1; s2a[1][j] += I1 * I1;
    }
  }
  int lo4 = (l >> 4) * 4;
#pragma unroll
  for (int g = 0; g < 2; ++g)
#pragma unroll
    for (int j = 0; j < 4; ++j) {
      int v1 = s1a[g][j], v2 = s2a[g][j];
      v1 += __shfl_xor(v1, 1); v1 += __shfl_xor(v1, 2);
      v1 += __shfl_xor(v1, 4); v1 += __shfl_xor(v1, 8);
      v2 += __shfl_xor(v2, 1); v2 += __shfl_xor(v2, 2);
      v2 += __shfl_xor(v2, 4); v2 += __shfl_xor(v2, 8);
      if ((l & 15) == 0) {
        int c = ch * 32 + g * 16 + lo4 + j;
        sh1[wv >> 1][c] = v1; sh2[wv >> 1][c] = v2;   // waves (0,1) / (2,3) disjoint c
      }
    }
  __syncthreads();
  if (t < 64) {
    long long a1 = (long long)sh1[0][t] + sh1[1][t];
    long long a2 = (long long)sh2[0][t] + sh2[1][t];
    atomicAdd(&S1[t], (u64)a1);
    atomicAdd(&S2[t], (u64)a2);
  }
}

__global__ __launch_bounds__(256, 3) void k_final(const float* __restrict__ x,
                                                  const unsigned char* __restrict__ xi8,
                                                  const unsigned char* __restrict__ wi8,
                                                  const u64* __restrict__ S1,
                                                  const u64* __restrict__ S2,
                                                  const float* __restrict__ alpha9,
                                                  const float* __restrict__ gamma,
                                                  const float* __restrict__ beta,
                                                  float* __restrict__ out) {
  __shared__ float2 scb[64];
  int b = blockIdx.x, t = threadIdx.x, wv = t >> 6, l = t & 63;
  if (t < 64) {
    float asum = 0.f;
#pragma unroll
    for (int k = 0; k < 9; ++k) asum += alpha9[k * 64 + t];
    double al = (double)asum * (1.0 / 576.0);
    long long s1v = (long long)S1[t], s2v = (long long)S2[t];
    double inv = 1.0 / (double)NPIX;
    double mean = (double)s1v * inv;
    double var = (double)s2v * inv - mean * mean;
    double sc = (double)gamma[t] * al / sqrt(al * al * var + 1e-5);
    scb[t] = make_float2((float)sc, (float)((double)beta[t] - sc * mean));
  }
  __syncthreads();

  int tid = b * 4 + wv;
  int row = tid >> 1, ch = tid & 1;
  int n = row / 112, h = row % 112;
  int lo = (l & 15) * 64 + (l >> 4) * 16;
  v4i A[2][9];
#pragma unroll
  for (int g = 0; g < 2; ++g)
#pragma unroll
    for (int k = 0; k < 9; ++k)
      A[g][k] = *reinterpret_cast<const v4i*>(wi8 + k * 4096 + (ch * 2 + g) * 1024 + lo);

  int lo4 = (l >> 4) * 4;
  float2 sb[2][4];                      // per-lane scale/bias, hoisted out of loop
#pragma unroll
  for (int g = 0; g < 2; ++g)
#pragma unroll
    for (int j = 0; j < 4; ++j) sb[g][j] = scb[ch * 32 + g * 16 + lo4 + j];

  const unsigned char* rowp = xi8 + (size_t)n * PNB + (size_t)(h + 1) * PRB + 64 + lo;
  // per-lane x/out base for cout block (ch*32 + lo4), pixel (h, l&15)
  size_t pixbase = (size_t)(n * 64 + ch * 32 + lo4) * HW + (size_t)h * 112 + (l & 15);
  const float* xb = x + pixbase;
  float* ob = out + pixbase;

#pragma unroll 2
  for (int wt = 0; wt < 7; ++wt) {
    const unsigned char* bp = rowp + wt * 1024;
    v4i B[9];
#pragma unroll
    for (int k = 0; k < 9; ++k) {
      int dh = k / 3 - 1, dw = k % 3 - 1;
      B[k] = *reinterpret_cast<const v4i*>(bp + dh * PRB + dw * 64);
    }
    float xv[2][4];                      // prefetch residual before MFMAs
#pragma unroll
    for (int g = 0; g < 2; ++g)
#pragma unroll
      for (int j = 0; j < 4; ++j)
        xv[g][j] = xb[(size_t)(g * 16 + j) * HW + wt * 16];
    v4i acc0 = {0,0,0,0}, acc1 = {0,0,0,0};
    MFMA9_2(acc0, acc1)
#pragma unroll
    for (int j = 0; j < 4; ++j) {
      float o0 = fmaf((float)acc0[j], sb[0][j].x, sb[0][j].y);
      o0 = fminf(fmaxf(o0, -1.f), 1.f) + xv[0][j];
      ob[(size_t)j * HW + wt * 16] = o0;
      float o1 = fmaf((float)acc1[j], sb[1][j].x, sb[1][j].y);
      o1 = fminf(fmaxf(o1, -1.f), 1.f) + xv[1][j];
      ob[(size_t)(16 + j) * HW + wt * 16] = o1;
    }
  }
}

// ---------------------------------------------------------------------------
extern "C" void kernel_launch(void* const* d_in, const int* in_sizes, int n_in,
                              void* d_out, int out_size, void* d_ws, size_t ws_size,
                              hipStream_t stream) {
  const float* x     = (const float*)d_in[0];
  const float* W     = (const float*)d_in[1];
  const float* gamma = (const float*)d_in[2];
  const float* beta  = (const float*)d_in[3];
  float* out = (float*)d_out;

  char* ws = (char*)d_ws;
  u64*           S1     = (u64*)(ws + 0);      // 64 * 8 B
  u64*           S2     = (u64*)(ws + 512);    // 64 * 8 B
  float*         alpha9 = (float*)(ws + 1024); // 576 * 4 B
  unsigned char* wi8    = (unsigned char*)(ws + 4096);   // 9*64*64 = 36864 B
  unsigned char* xi8    = (unsigned char*)(ws + 65536);  // 32*PNB = 26.6 MB

  hipLaunchKernelGGL(k_pack, dim3(817), dim3(256), 0, stream,
                     x, W, xi8, wi8, alpha9, (u64*)ws);
  hipLaunchKernelGGL(k_stats, dim3(1792), dim3(256), 0, stream, xi8, wi8, S1, S2);
  hipLaunchKernelGGL(k_final, dim3(1792), dim3(256), 0, stream,
                     x, xi8, wi8, S1, S2, alpha9, gamma, beta, out);
}